// Round 5
// baseline (84.894 us; speedup 1.0000x reference)
//
#include <hip/hip_runtime.h>

#define HHI 1024
#define WWI 1024
#define NI  16
#define HWSZ (HHI * WWI)
#define EPSF  1.1920929e-07f
#define EPS64 7.62939453125e-06f   // 64*EPSF (exact)
#define T1 0.3249196962329063f     // tan(pi/10)
#define T2 1.3763819204711735f     // tan(3pi/10)

#define SW 256                     // cols per wave (64 lanes x 4)
#define RW 16                      // output rows per wave
#define GX  (WWI / SW)             // 4
#define GYB (HHI / (RW * 4))       // 16 (block = 4 waves = 64 rows)
#define NB  (GX * GYB * NI)        // 1024 blocks
#define FR_IMG 8176                // frame pixels per image (2px border)
#define FR_TOT (FR_IMG * NI)       // 130816

__device__ __forceinline__ int clampi(int v, int hi) { return v < 0 ? 0 : (v > hi ? hi : v); }
__device__ __forceinline__ int refli(int v, int n)  { return v < 0 ? -v : (v >= n ? 2*n-2-v : v); }
__device__ __forceinline__ float frcp(float x) { return __builtin_amdgcn_rcpf(x); }

// One pipeline stage: true row -> H-ring[POS]; pred row -> E-ring[POS]; emit output row.
// POS is a compile-time literal 0..4; all ring indices static (mod-5).
#define STAGE(POS, IDX, DOPRED, DOOUT) do {                                           \
    const int i_ = (IDX);                                                             \
    {                                                                                 \
        const int gy_ = clampi(Y0 - 2 + i_, HHI - 1);                                 \
        const float* trow_ = timg + (size_t)gy_ * WWI;                                \
        const float4 cq_ = *(const float4*)(trow_ + x0);                              \
        const float2 lo_ = *(const float2*)(trow_ + cm2);                             \
        const float2 hi_ = *(const float2*)(trow_ + cp4);                             \
        float wv_[8];                                                                 \
        wv_[0] = xokl ? lo_.x : cq_.x;                                                \
        wv_[1] = xokl ? lo_.y : cq_.x;                                                \
        wv_[2] = cq_.x; wv_[3] = cq_.y; wv_[4] = cq_.z; wv_[5] = cq_.w;               \
        wv_[6] = xokr ? hi_.x : cq_.w;                                                \
        wv_[7] = xokr ? hi_.y : cq_.w;                                                \
        _Pragma("unroll")                                                             \
        for (int k = 0; k < 4; ++k) {                                                 \
            float s04 = wv_[k] + wv_[k+4];                                            \
            float s13 = wv_[k+1] + wv_[k+3];                                          \
            H1[POS][k] = s04 - 2.f * wv_[k+2];                                        \
            H2[POS][k] = s04 + 4.f * s13 + 6.f * wv_[k+2];                            \
            H3[POS][k] = (wv_[k+4] - wv_[k]) + 2.f * (wv_[k+3] - wv_[k+1]);           \
        }                                                                             \
    }                                                                                 \
    if (DOPRED) {                                                                     \
        const int gp_ = refli(Y0 + i_ - 3, HHI);                                      \
        const float* prow_ = pimg + (size_t)gp_ * WWI;                                \
        const float4 pq_ = *(const float4*)(prow_ + x0);                              \
        const float pl_ = prow_[cm1];                                                 \
        const float pr_ = prow_[cp4s];                                                \
        Ec[POS][0] = __expf(pq_.x); Ec[POS][1] = __expf(pq_.y);                       \
        Ec[POS][2] = __expf(pq_.z); Ec[POS][3] = __expf(pq_.w);                       \
        El[POS] = __expf(xokl ? pl_ : pq_.y);  /* reflect: col -1 -> col 1 */         \
        Er[POS] = __expf(xokr ? pr_ : pq_.z);  /* reflect: 1024 -> 1022  */           \
    }                                                                                 \
    if (DOOUT) {                                                                      \
        const int y_ = Y0 + i_ - 4;                                                   \
        const bool my_ = (y_ >= 2) & (y_ <= HHI - 3);                                 \
        const int q0=(POS+1)%5, q1=(POS+2)%5, q2=(POS+3)%5, q3=(POS+4)%5, q4=POS;     \
        const int e0=(POS+3)%5, e1=(POS+4)%5, e2=POS;                                 \
        _Pragma("unroll")                                                             \
        for (int k = 0; k < 4; ++k) {                                                 \
            float gxx = (H1[q0][k]+H1[q4][k]) + 4.f*(H1[q1][k]+H1[q3][k]) + 6.f*H1[q2][k]; \
            float gyy = (H2[q0][k]+H2[q4][k]) - 2.f*H2[q2][k];                        \
            float gxy = (H3[q4][k]-H3[q0][k]) + 2.f*(H3[q3][k]-H3[q1][k]);            \
            float sarg = EPS64 - gxy;                                                 \
            float num = (sarg > 0.f) ? gyy : ((sarg < 0.f) ? -gyy : 0.f);             \
            float v = num * frcp(gxx + EPS64);                                        \
            bool c2v = (v > T2);                                                      \
            bool c1v = (v > T1) & !c2v;                                               \
            bool c0v = (v >= -T1) & (v <= T1);                                        \
            bool c3v = (v < -T2);                                                     \
            bool have = c2v | c1v | c0v | c3v;  /* NaN -> none */                     \
            float r0m = (k==0) ? El[e0] : Ec[e0][(k>0)?k-1:0];                        \
            float r0c = Ec[e0][k];                                                    \
            float r0p = (k==3) ? Er[e0] : Ec[e0][(k<3)?k+1:3];                        \
            float r1m = (k==0) ? El[e1] : Ec[e1][(k>0)?k-1:0];                        \
            float r1c = Ec[e1][k];                                                    \
            float r1p = (k==3) ? Er[e1] : Ec[e1][(k<3)?k+1:3];                        \
            float r2m = (k==0) ? El[e2] : Ec[e2][(k>0)?k-1:0];                        \
            float r2c = Ec[e2][k];                                                    \
            float r2p = (k==3) ? Er[e2] : Ec[e2][(k<3)?k+1:3];                        \
            float d1 = c0v ? r1m : (c2v ? r0c : (c1v ? r0p : r0m));                   \
            float d2 = c0v ? r1p : (c2v ? r2c : (c1v ? r2m : r2p));                   \
            float ec = r1c;                                                           \
            float val = ec * frcp(d1 + ec + d2 + EPSF);                               \
            const int x_ = x0 + k;                                                    \
            bool ok = have & my_ & (x_ >= 2) & (x_ <= WWI - 3);                       \
            term += ok ? val : 0.f;                                                   \
        }                                                                             \
    }                                                                                 \
} while (0)

template <bool USE_WS>
__global__ __launch_bounds__(256, 4) void nms_main(
    const float* __restrict__ tru, const float* __restrict__ prd,
    float* __restrict__ partial)
{
    __shared__ float sred[4];
    const int tid  = threadIdx.x;
    const int lane = tid & 63;
    const int wave = tid >> 6;
    const int z = blockIdx.z;
    const float* timg = tru + (size_t)z * HWSZ;
    const float* pimg = prd + (size_t)z * HWSZ;
    float term = 0.f;

    // -------- interior: per-wave 256x16 tile, float4 per lane, reg rings --------
    const int X0 = blockIdx.x * SW;
    const int x0 = X0 + lane * 4;
    const int Y0 = blockIdx.y * (RW * 4) + wave * RW;
    const bool xokl = (x0 >= 2);            // left halo loads valid
    const bool xokr = (x0 + 4 <= WWI - 1);  // right halo loads valid
    const int cm2  = xokl ? x0 - 2 : 0;     // even -> 8B aligned
    const int cp4  = xokr ? x0 + 4 : WWI - 2;
    const int cm1  = xokl ? x0 - 1 : 0;
    const int cp4s = xokr ? x0 + 4 : WWI - 1;

    float H1[5][4], H2[5][4], H3[5][4];
    float Ec[5][4], El[5], Er[5];

    // prologue: stage rows i=0..4 (pred from i=2), first output at i=4 (y=Y0)
    STAGE(0, 0, 0, 0);
    STAGE(1, 1, 0, 0);
    STAGE(2, 2, 1, 0);
    STAGE(3, 3, 1, 0);
    STAGE(4, 4, 1, 1);
    #pragma unroll 1
    for (int g = 1; g < 4; ++g) {
        const int ib = g * 5;
        STAGE(0, ib + 0, 1, 1);
        STAGE(1, ib + 1, 1, 1);
        STAGE(2, ib + 2, 1, 1);
        STAGE(3, ib + 3, 1, 1);
        STAGE(4, ib + 4, 1, 1);
    }

    // -------- frame epilogue: 2-px border, exact nested replicate-pad cascade,
    // distributed evenly over all waves (32 pixels per wave, lanes 0..31) ----
    {
        const int wid = (((z * gridDim.y) + blockIdx.y) * gridDim.x + blockIdx.x) * 4 + wave;
        int fp = wid * 32 + lane;
        const bool valid = (lane < 32) && (fp < FR_TOT);
        if (fp >= FR_TOT) fp = FR_TOT - 1;
        const int fz = fp / FR_IMG;          // const divisor -> magic mul
        const int p  = fp - fz * FR_IMG;
        const float* ftim = tru + (size_t)fz * HWSZ;
        const float* fpim = prd + (size_t)fz * HWSZ;
        int y, x;
        if (p < 2048)      { y = p >> 10;                   x = p & 1023; }
        else if (p < 4096) { y = 1022 + ((p - 2048) >> 10); x = p & 1023; }
        else { int q = p - 4096; y = 2 + (q >> 2); int xi = q & 3; x = (xi < 2) ? xi : 1020 + xi; }

        int R1[3], C1[3], R2[3][3], C2[3][3];
        #pragma unroll
        for (int a = 0; a < 3; ++a) { R1[a] = clampi(y + a - 1, HHI - 1); C1[a] = clampi(x + a - 1, WWI - 1); }
        #pragma unroll
        for (int a = 0; a < 3; ++a)
            #pragma unroll
            for (int e = 0; e < 3; ++e) {
                R2[a][e] = clampi(R1[a] + e - 1, HHI - 1);
                C2[a][e] = clampi(C1[a] + e - 1, WWI - 1);
            }
        const int hx[3] = {-1, 0, 1}, vx[3] = {1, 2, 1};
        const int hy[3] = {1, 2, 1},  vy[3] = {-1, 0, 1};
        float gxu[3][3], gyu[3][3];
        #pragma unroll
        for (int a = 0; a < 3; ++a)
            #pragma unroll
            for (int b = 0; b < 3; ++b) {
                float sx = 0.f, sy = 0.f;
                #pragma unroll
                for (int e = 0; e < 3; ++e)
                    #pragma unroll
                    for (int f = 0; f < 3; ++f) {
                        const int wx = hx[f] * vx[e], wy = hy[f] * vy[e];
                        if (wx | wy) {
                            float tv = ftim[(size_t)R2[a][e] * WWI + C2[b][f]];
                            if (wx) sx += (float)wx * tv;
                            if (wy) sy += (float)wy * tv;
                        }
                    }
                gxu[a][b] = sx; gyu[a][b] = sy;
            }
        float gxx = 0.f, gxy = 0.f, gyy = 0.f;
        #pragma unroll
        for (int a = 0; a < 3; ++a)
            #pragma unroll
            for (int b = 0; b < 3; ++b) {
                const int w1 = hx[b] * vx[a], w2 = hy[b] * vy[a];
                if (w1) { gxx += (float)w1 * gxu[a][b]; gxy += (float)w1 * gyu[a][b]; }
                if (w2) { gyy += (float)w2 * gyu[a][b]; }
            }
        float sarg = EPS64 - gxy;           // x64 unnormalized throughout
        float num = (sarg > 0.f) ? gyy : ((sarg < 0.f) ? -gyy : 0.f);
        float v = num * frcp(gxx + EPS64);
        bool c2v = (v > T2);
        bool c1v = (v > T1) & !c2v;
        bool c0v = (v >= -T1) & (v <= T1);
        bool c3v = (v < -T2);
        bool have = c2v | c1v | c0v | c3v;
        int r1 = c0v ? y : refli(y - 1, HHI);
        int r2 = c0v ? y : refli(y + 1, HHI);
        int xm = refli(x - 1, WWI), xp = refli(x + 1, WWI);
        int co1 = c2v ? x : (c1v ? xp : xm);
        int co2 = c2v ? x : (c1v ? xm : xp);
        float ecf = __expf(fpim[(size_t)y * WWI + x]);
        float d1f = __expf(fpim[(size_t)r1 * WWI + co1]);
        float d2f = __expf(fpim[(size_t)r2 * WWI + co2]);
        float fval = ecf * frcp(d1f + ecf + d2f + EPSF);
        term += (have & valid) ? fval : 0.f;
    }

    // -------- block reduction --------
    for (int off = 32; off; off >>= 1) term += __shfl_down(term, off, 64);
    if (lane == 0) sred[wave] = term;
    __syncthreads();
    if (tid == 0) {
        float b = sred[0] + sred[1] + sred[2] + sred[3];
        if (USE_WS) {
            partial[((size_t)z * gridDim.y + blockIdx.y) * gridDim.x + blockIdx.x] = b;
        } else {
            atomicAdd(partial, b);
        }
    }
}

__global__ __launch_bounds__(1024) void reduce_kernel(
    const float* __restrict__ partial, float* __restrict__ out)
{
    __shared__ float s_red[16];
    float s = 0.f;
    for (int i = threadIdx.x; i < NB; i += 1024) s += partial[i];
    for (int off = 32; off; off >>= 1) s += __shfl_down(s, off, 64);
    if ((threadIdx.x & 63) == 0) s_red[threadIdx.x >> 6] = s;
    __syncthreads();
    if (threadIdx.x == 0) {
        float b = 0.f;
        #pragma unroll
        for (int i = 0; i < 16; ++i) b += s_red[i];
        out[0] = b;
    }
}

extern "C" void kernel_launch(void* const* d_in, const int* in_sizes, int n_in,
                              void* d_out, int out_size, void* d_ws, size_t ws_size,
                              hipStream_t stream) {
    const float* tru = (const float*)d_in[0];
    const float* prd = (const float*)d_in[1];
    float* out = (float*)d_out;
    dim3 grid(GX, GYB, NI);
    dim3 block(256, 1, 1);
    if (ws_size >= (size_t)NB * sizeof(float)) {
        float* ws = (float*)d_ws;
        hipLaunchKernelGGL(nms_main<true>, grid, block, 0, stream, tru, prd, ws);
        hipLaunchKernelGGL(reduce_kernel, dim3(1), dim3(1024), 0, stream, ws, out);
    } else {
        hipMemsetAsync(out, 0, sizeof(float), stream);
        hipLaunchKernelGGL(nms_main<false>, grid, block, 0, stream, tru, prd, out);
    }
}

// Round 6
// 79.776 us; speedup vs baseline: 1.0642x; 1.0642x over previous
//
#include <hip/hip_runtime.h>

#define HHI 1024
#define WWI 1024
#define NI  16
#define HWSZ (HHI * WWI)
#define EPSF  1.1920929e-07f
#define EPS64 7.62939453125e-06f   // 64*EPSF (exact)
#define T1 0.3249196962329063f     // tan(pi/10)
#define T2 1.3763819204711735f     // tan(3pi/10)

#define SW 128                     // cols per wave (64 lanes x 2)
#define RW 16                      // output rows per wave
#define GX  (WWI / SW)             // 8
#define GYB (HHI / (RW * 4))       // 16 (block = 4 waves stacked = 64 rows)
#define NB  (GX * GYB * NI)        // 2048 blocks
#define FR_IMG 8176                // frame pixels per image (2px border)
#define FR_TOT (FR_IMG * NI)       // 130816

__device__ __forceinline__ int clampi(int v, int hi) { return v < 0 ? 0 : (v > hi ? hi : v); }
__device__ __forceinline__ int refli(int v, int n)  { return v < 0 ? -v : (v >= n ? 2*n-2-v : v); }
__device__ __forceinline__ float frcp(float x) { return __builtin_amdgcn_rcpf(x); }

// One pipeline stage. POS is a literal 0..4; all ring indices compile-time.
// Lane owns cols x0, x0+1. True window wv[0..5] = t[x0-2 .. x0+3].
// E ring row = exp(pred) at cols {x0-1, x0, x0+1, x0+2}.
#define STAGE(POS, IDX, DOPRED, DOOUT) do {                                           \
    const int i_ = (IDX);                                                             \
    {                                                                                 \
        const int gy_ = clampi(Y0 - 2 + i_, HHI - 1);                                 \
        const float* trow_ = timg + (size_t)gy_ * WWI;                                \
        const float2 cq_ = *(const float2*)(trow_ + x0);                              \
        const float2 lo_ = *(const float2*)(trow_ + cm2);                             \
        const float2 hi_ = *(const float2*)(trow_ + cp2);                             \
        const float w0 = xokl ? lo_.x : cq_.x;                                        \
        const float w1 = xokl ? lo_.y : cq_.x;                                        \
        const float w2 = cq_.x, w3 = cq_.y;                                           \
        const float w4 = xokr ? hi_.x : cq_.y;                                        \
        const float w5 = xokr ? hi_.y : cq_.y;                                        \
        const float s04 = w0 + w4, s13 = w1 + w3;                                     \
        H1[POS][0] = s04 - 2.f * w2;                    /* [1,0,-2,0,1]  */           \
        H2[POS][0] = s04 + 4.f * s13 + 6.f * w2;        /* [1,4,6,4,1]   */           \
        H3[POS][0] = (w4 - w0) + 2.f * (w3 - w1);       /* [-1,-2,0,2,1] */           \
        const float t04 = w1 + w5, t13 = w2 + w4;                                     \
        H1[POS][1] = t04 - 2.f * w3;                                                  \
        H2[POS][1] = t04 + 4.f * t13 + 6.f * w3;                                      \
        H3[POS][1] = (w5 - w1) + 2.f * (w4 - w2);                                     \
    }                                                                                 \
    if (DOPRED) {                                                                     \
        const int gp_ = refli(Y0 + i_ - 3, HHI);                                      \
        const float* prow_ = pimg + (size_t)gp_ * WWI;                                \
        const float2 pc_ = *(const float2*)(prow_ + x0);                              \
        const float2 pl_ = *(const float2*)(prow_ + cm2);                             \
        const float2 ph_ = *(const float2*)(prow_ + cp2);                             \
        E[POS][0] = __expf(xokl ? pl_.y : pc_.y);   /* x0-1; reflect -1 -> 1 */       \
        E[POS][1] = __expf(pc_.x);                                                    \
        E[POS][2] = __expf(pc_.y);                                                    \
        E[POS][3] = __expf(xokr ? ph_.x : pc_.x);   /* x0+2; reflect 1024 -> 1022 */  \
    }                                                                                 \
    if (DOOUT) {                                                                      \
        const int y_ = Y0 + i_ - 4;                                                   \
        const bool my_ = (y_ >= 2) & (y_ <= HHI - 3);                                 \
        const int q0=(POS+1)%5, q1=(POS+2)%5, q2=(POS+3)%5, q3=(POS+4)%5, q4=POS;     \
        const int eT=(POS+3)%5, eM=(POS+4)%5, eB=POS;                                 \
        _Pragma("unroll")                                                             \
        for (int k = 0; k < 2; ++k) {                                                 \
            float gxx = (H1[q0][k]+H1[q4][k]) + 4.f*(H1[q1][k]+H1[q3][k]) + 6.f*H1[q2][k]; \
            float gyy = (H2[q0][k]+H2[q4][k]) - 2.f*H2[q2][k];                        \
            float gxy = (H3[q4][k]-H3[q0][k]) + 2.f*(H3[q3][k]-H3[q1][k]);            \
            float sarg = EPS64 - gxy;                                                 \
            float num = (sarg > 0.f) ? gyy : ((sarg < 0.f) ? -gyy : 0.f);             \
            float v = num * frcp(gxx + EPS64);                                        \
            bool c2v = (v > T2);                                                      \
            bool c1v = (v > T1) & !c2v;                                               \
            bool c0v = (v >= -T1) & (v <= T1);                                        \
            bool c3v = (v < -T2);                                                     \
            bool have = c2v | c1v | c0v | c3v;   /* NaN -> none */                    \
            float d1 = c0v ? E[eM][k]   : (c2v ? E[eT][k+1] : (c1v ? E[eT][k+2] : E[eT][k])); \
            float d2 = c0v ? E[eM][k+2] : (c2v ? E[eB][k+1] : (c1v ? E[eB][k]   : E[eB][k+2])); \
            float ec = E[eM][k+1];                                                    \
            float val = ec * frcp(d1 + ec + d2 + EPSF);                               \
            const int x_ = x0 + k;                                                    \
            bool ok = have & my_ & (x_ >= 2) & (x_ <= WWI - 3);                       \
            term += ok ? val : 0.f;                                                   \
        }                                                                             \
    }                                                                                 \
} while (0)

template <bool USE_WS>
__global__ __launch_bounds__(256, 4) void nms_main(
    const float* __restrict__ tru, const float* __restrict__ prd,
    float* __restrict__ partial)
{
    __shared__ float sred[4];
    const int tid  = threadIdx.x;
    const int lane = tid & 63;
    const int wave = tid >> 6;
    const int z = blockIdx.z;
    const float* timg = tru + (size_t)z * HWSZ;
    const float* pimg = prd + (size_t)z * HWSZ;
    float term = 0.f;

    // -------- interior: per-wave 128x16 tile, 2 cols/lane, register rings --------
    const int x0 = blockIdx.x * SW + lane * 2;
    const int Y0 = blockIdx.y * (RW * 4) + wave * RW;
    const bool xokl = (x0 >= 2);
    const bool xokr = (x0 <= WWI - 4);
    const int cm2 = xokl ? x0 - 2 : 0;        // 8B-aligned (x0 even)
    const int cp2 = xokr ? x0 + 2 : WWI - 2;  // 8B-aligned

    float H1[5][2], H2[5][2], H3[5][2];
    float E[5][4];

    // stages i=0..19: true rows Y0-2..Y0+17; pred from i=2; outputs y=Y0..Y0+15
    STAGE(0, 0, 0, 0);
    STAGE(1, 1, 0, 0);
    STAGE(2, 2, 1, 0);
    STAGE(3, 3, 1, 0);
    STAGE(4, 4, 1, 1);
    #pragma unroll 1
    for (int g = 1; g < 4; ++g) {
        const int ib = g * 5;
        STAGE(0, ib + 0, 1, 1);
        STAGE(1, ib + 1, 1, 1);
        STAGE(2, ib + 2, 1, 1);
        STAGE(3, ib + 3, 1, 1);
        STAGE(4, ib + 4, 1, 1);
    }

    // -------- frame epilogue: 2-px border, exact nested replicate-pad cascade,
    // 16 pixels per wave on lanes 0..15 --------
    {
        const int wid = (((z * gridDim.y) + blockIdx.y) * gridDim.x + blockIdx.x) * 4 + wave;
        int fp = wid * 16 + lane;
        const bool valid = (lane < 16) && (fp < FR_TOT);
        if (fp >= FR_TOT) fp = FR_TOT - 1;
        const int fz = fp / FR_IMG;          // const divisor -> magic mul
        const int p  = fp - fz * FR_IMG;
        const float* ftim = tru + (size_t)fz * HWSZ;
        const float* fpim = prd + (size_t)fz * HWSZ;
        int y, x;
        if (p < 2048)      { y = p >> 10;                   x = p & 1023; }
        else if (p < 4096) { y = 1022 + ((p - 2048) >> 10); x = p & 1023; }
        else { int q = p - 4096; y = 2 + (q >> 2); int xi = q & 3; x = (xi < 2) ? xi : 1020 + xi; }

        int R1[3], C1[3], R2[3][3], C2[3][3];
        #pragma unroll
        for (int a = 0; a < 3; ++a) { R1[a] = clampi(y + a - 1, HHI - 1); C1[a] = clampi(x + a - 1, WWI - 1); }
        #pragma unroll
        for (int a = 0; a < 3; ++a)
            #pragma unroll
            for (int e = 0; e < 3; ++e) {
                R2[a][e] = clampi(R1[a] + e - 1, HHI - 1);
                C2[a][e] = clampi(C1[a] + e - 1, WWI - 1);
            }
        const int hx[3] = {-1, 0, 1}, vx[3] = {1, 2, 1};
        const int hy[3] = {1, 2, 1},  vy[3] = {-1, 0, 1};
        float gxu[3][3], gyu[3][3];
        #pragma unroll
        for (int a = 0; a < 3; ++a)
            #pragma unroll
            for (int b = 0; b < 3; ++b) {
                float sx = 0.f, sy = 0.f;
                #pragma unroll
                for (int e = 0; e < 3; ++e)
                    #pragma unroll
                    for (int f = 0; f < 3; ++f) {
                        const int wx = hx[f] * vx[e], wy = hy[f] * vy[e];
                        if (wx | wy) {
                            float tv = ftim[(size_t)R2[a][e] * WWI + C2[b][f]];
                            if (wx) sx += (float)wx * tv;
                            if (wy) sy += (float)wy * tv;
                        }
                    }
                gxu[a][b] = sx; gyu[a][b] = sy;
            }
        float gxx = 0.f, gxy = 0.f, gyy = 0.f;
        #pragma unroll
        for (int a = 0; a < 3; ++a)
            #pragma unroll
            for (int b = 0; b < 3; ++b) {
                const int w1 = hx[b] * vx[a], w2 = hy[b] * vy[a];
                if (w1) { gxx += (float)w1 * gxu[a][b]; gxy += (float)w1 * gyu[a][b]; }
                if (w2) { gyy += (float)w2 * gyu[a][b]; }
            }
        float sarg = EPS64 - gxy;            // x64 unnormalized throughout
        float num = (sarg > 0.f) ? gyy : ((sarg < 0.f) ? -gyy : 0.f);
        float v = num * frcp(gxx + EPS64);
        bool c2v = (v > T2);
        bool c1v = (v > T1) & !c2v;
        bool c0v = (v >= -T1) & (v <= T1);
        bool c3v = (v < -T2);
        bool have = c2v | c1v | c0v | c3v;
        int r1 = c0v ? y : refli(y - 1, HHI);
        int r2 = c0v ? y : refli(y + 1, HHI);
        int xm = refli(x - 1, WWI), xp = refli(x + 1, WWI);
        int co1 = c2v ? x : (c1v ? xp : xm);
        int co2 = c2v ? x : (c1v ? xm : xp);
        float ecf = __expf(fpim[(size_t)y * WWI + x]);
        float d1f = __expf(fpim[(size_t)r1 * WWI + co1]);
        float d2f = __expf(fpim[(size_t)r2 * WWI + co2]);
        float fval = ecf * frcp(d1f + ecf + d2f + EPSF);
        term += (have & valid) ? fval : 0.f;
    }

    // -------- block reduction --------
    for (int off = 32; off; off >>= 1) term += __shfl_down(term, off, 64);
    if (lane == 0) sred[wave] = term;
    __syncthreads();
    if (tid == 0) {
        float b = sred[0] + sred[1] + sred[2] + sred[3];
        if (USE_WS) {
            partial[((size_t)z * gridDim.y + blockIdx.y) * gridDim.x + blockIdx.x] = b;
        } else {
            atomicAdd(partial, b);
        }
    }
}

__global__ __launch_bounds__(1024) void reduce_kernel(
    const float* __restrict__ partial, float* __restrict__ out)
{
    __shared__ float s_red[16];
    float s = 0.f;
    for (int i = threadIdx.x; i < NB; i += 1024) s += partial[i];
    for (int off = 32; off; off >>= 1) s += __shfl_down(s, off, 64);
    if ((threadIdx.x & 63) == 0) s_red[threadIdx.x >> 6] = s;
    __syncthreads();
    if (threadIdx.x == 0) {
        float b = 0.f;
        #pragma unroll
        for (int i = 0; i < 16; ++i) b += s_red[i];
        out[0] = b;
    }
}

extern "C" void kernel_launch(void* const* d_in, const int* in_sizes, int n_in,
                              void* d_out, int out_size, void* d_ws, size_t ws_size,
                              hipStream_t stream) {
    const float* tru = (const float*)d_in[0];
    const float* prd = (const float*)d_in[1];
    float* out = (float*)d_out;
    dim3 grid(GX, GYB, NI);
    dim3 block(256, 1, 1);
    if (ws_size >= (size_t)NB * sizeof(float)) {
        float* ws = (float*)d_ws;
        hipLaunchKernelGGL(nms_main<true>, grid, block, 0, stream, tru, prd, ws);
        hipLaunchKernelGGL(reduce_kernel, dim3(1), dim3(1024), 0, stream, ws, out);
    } else {
        hipMemsetAsync(out, 0, sizeof(float), stream);
        hipLaunchKernelGGL(nms_main<false>, grid, block, 0, stream, tru, prd, out);
    }
}